// Round 7
// baseline (3970.921 us; speedup 1.0000x reference)
//
#include <hip/hip_runtime.h>
#include <math.h>

// ResidualQuantizer: 8 stages of VQ over B=32768 rows, D=256, K=1024.
// Outputs (flat f32): z_q_sum[32768*256], codes[32768*8] (as float), loss[1].
// Numerics: bit-exact numpy fp32 emulation for the argmin (proven r2..r6):
//   dist = fl(fl(z2 + e2_k) - 2*ze_k), ze_k = ascending-d fp32 FMA chain,
//   e2_k = numpy pairwise sum, argmin = first occurrence of min.
// Round 7: reg-staged 16k-wide windows (T14). Global loads for window c+1
// are issued DURING window c's 1024-fmaf compute (latency fully covered),
// published via ds_write between two raw barriers. 2 barriers / 1024 fmaf,
// single 32KB Es buffer, conflict-free immediate-offset ev reads.

#define NQ 8
#define KCODES 1024
#define DDIM 256
#define BN 32768
#define TM 32            // rows per block
#define THREADS 256
#define WINK 16          // k floats per staged window
#define NWIN (DDIM / WINK)   // 16
#define CPP 512          // codes per pass
#define NPASS 2

#define WS_E2    0
#define WS_LOSSP 32768
#define WS_PK    40960
#define WS_NEED  (40960 + (size_t)NQ * KCODES * DDIM * 4)

// ---- e2[s*K+k] = np.sum(cb[s][k]**2), exact numpy pairwise emulation ----
__global__ void e2_kernel(const float* __restrict__ cb, float* __restrict__ e2) {
    __shared__ float X[16][DDIM];
    const int t = threadIdx.x;
    const int cbase = blockIdx.x * 16;
    {
        const float4* src = (const float4*)(cb + (size_t)cbase * DDIM);
        float4* dst = (float4*)(&X[0][0]);
        #pragma unroll
        for (int n = 0; n < 4; ++n) dst[t + n * THREADS] = src[t + n * THREADS];
    }
    __syncthreads();
    const int lane = t & 63;
    const int code = (t >> 6) * 4 + (lane >> 4);
    const int u = lane & 15, j = u & 7, h = u >> 3;
    const float* x = &X[code][h * 128];
    float r = __fmul_rn(x[j], x[j]);
    for (int i = 1; i < 16; ++i) {
        float v = x[8 * i + j];
        r = __fadd_rn(r, __fmul_rn(v, v));
    }
    float o;
    o = __shfl_xor(r, 1); r = __fadd_rn(r, o);
    o = __shfl_xor(r, 2); r = __fadd_rn(r, o);
    o = __shfl_xor(r, 4); r = __fadd_rn(r, o);
    o = __shfl_xor(r, 8); r = __fadd_rn(r, o);
    if (u == 0) e2[cbase + code] = r;
}

// ---- pack cb: pk[(sp*64+q)*512 + u] = cb[sp*512+u][q*4 .. q*4+4) ----
__global__ void pack_kernel(const float* __restrict__ cb, float4* __restrict__ pk) {
    const int t = threadIdx.x;
    const int bid = blockIdx.x;          // (s*2+p)*64 + q  (q = k-quad index)
    const int q = bid & 63, sp = bid >> 6;
    const float* src = cb + (size_t)sp * 512 * DDIM + q * 4;
    float4* dst = pk + (size_t)bid * 512;
    #pragma unroll
    for (int n = 0; n < 2; ++n) {
        int u = n * 256 + t;
        dst[u] = *(const float4*)(src + (size_t)u * DDIM);
    }
}

template <bool PACKED>
__global__ __launch_bounds__(THREADS, 2) void rq_kernel(
    const float* __restrict__ zin, const float* __restrict__ cb,
    const float* __restrict__ e2g, const float4* __restrict__ pk,
    float* __restrict__ out, double* __restrict__ lossp)
{
    __shared__ float  Rs[TM][DDIM];        // 32 KB residual tile (persistent)
    __shared__ float4 Es[4 * 512];         // 32 KB window image [kq][code]
    __shared__ float  top1v[NPASS][TM];
    __shared__ int    top1i[NPASS][TM];
    __shared__ float  z2s[TM];
    __shared__ int    codes_s[TM];
    __shared__ double lredw[4];

    const int t    = threadIdx.x;
    const int l    = t & 63;
    const int w    = t >> 6;               // wave id; wave w owns rows w*8..w*8+7
    const size_t rowbase = (size_t)blockIdx.x * TM;
    const int row_u = t >> 3, oct = t & 7;

    // ---- load residual tile = z_e rows (coalesced) ----
    {
        const float4* src = (const float4*)(zin + rowbase * DDIM);
        float4* dst = (float4*)(&Rs[0][0]);
        #pragma unroll
        for (int n = 0; n < (TM * DDIM / 4) / THREADS; ++n)
            dst[t + n * THREADS] = src[t + n * THREADS];
    }
    __syncthreads();

    // ---- initial z2 per row (uniform shift: any fp32 order OK — proven) ----
    {
        const float4* rrow = (const float4*)(&Rs[row_u][oct * 32]);
        float z2n = 0.f;
        #pragma unroll
        for (int i = 0; i < 8; ++i) {
            float4 rv = rrow[i];
            z2n = fmaf(rv.x, rv.x, z2n); z2n = fmaf(rv.y, rv.y, z2n);
            z2n = fmaf(rv.z, rv.z, z2n); z2n = fmaf(rv.w, rv.w, z2n);
        }
        z2n += __shfl_xor(z2n, 1);
        z2n += __shfl_xor(z2n, 2);
        z2n += __shfl_xor(z2n, 4);
        if (oct == 0) z2s[row_u] = z2n;
    }
    double lacc = 0.0;

    for (int s = 0; s < NQ; ++s) {
        const float* cbs = cb + (size_t)s * KCODES * DDIM;

        for (int p = 0; p < NPASS; ++p) {
            const int code0 = p * CPP;
            const float4* sbp = pk + (size_t)(s * 2 + p) * 64 * 512;

            float acc[8][8];
            #pragma unroll
            for (int i = 0; i < 8; ++i)
                #pragma unroll
                for (int j = 0; j < 8; ++j) acc[i][j] = 0.f;

            // ---- prologue: issue window 0 loads into registers ----
            float4 st[4][2];
            #pragma unroll
            for (int kq = 0; kq < 4; ++kq)
                #pragma unroll
                for (int rep = 0; rep < 2; ++rep)
                    st[kq][rep] = PACKED
                        ? sbp[(size_t)kq * 512 + rep * 256 + t]
                        : *(const float4*)(cbs + (size_t)(code0 + rep * 256 + t) * DDIM + kq * 4);

            #pragma unroll 1
            for (int c = 0; c < NWIN; ++c) {
                // seam: st regs were issued a full step ago -> vmcnt(0) ~free
                asm volatile("s_waitcnt vmcnt(0)" ::: "memory");
                __builtin_amdgcn_s_barrier();      // all waves done reading win c-1
                __builtin_amdgcn_sched_barrier(0);
                // publish window c
                #pragma unroll
                for (int kq = 0; kq < 4; ++kq)
                    #pragma unroll
                    for (int rep = 0; rep < 2; ++rep)
                        Es[(kq * 2 + rep) * 256 + t] = st[kq][rep];
                asm volatile("s_waitcnt lgkmcnt(0)" ::: "memory");
                __builtin_amdgcn_s_barrier();      // window c visible block-wide
                __builtin_amdgcn_sched_barrier(0);

                const bool more = (c + 1 < NWIN);
                #pragma unroll
                for (int kq = 0; kq < 4; ++kq) {
                    if (more) {   // issue next window's loads; land under compute
                        if (PACKED) {
                            st[kq][0] = sbp[(size_t)((c + 1) * 4 + kq) * 512 + t];
                            st[kq][1] = sbp[(size_t)((c + 1) * 4 + kq) * 512 + 256 + t];
                        } else {
                            st[kq][0] = *(const float4*)(cbs + (size_t)(code0 + t) * DDIM
                                                         + (c + 1) * WINK + kq * 4);
                            st[kq][1] = *(const float4*)(cbs + (size_t)(code0 + 256 + t) * DDIM
                                                         + (c + 1) * WINK + kq * 4);
                        }
                    }
                    // ascending-d fp32 FMA chain (identical arithmetic to r2..r6)
                    float4 ev[8];
                    #pragma unroll
                    for (int j = 0; j < 8; ++j)
                        ev[j] = Es[kq * 512 + j * 64 + l];   // contiguous, imm offsets
                    #pragma unroll
                    for (int i = 0; i < 8; ++i) {
                        float4 rv = *(const float4*)(&Rs[w * 8 + i][c * WINK + kq * 4]);
                        #pragma unroll
                        for (int j = 0; j < 8; ++j) {
                            acc[i][j] = fmaf(rv.x, ev[j].x, acc[i][j]);
                            acc[i][j] = fmaf(rv.y, ev[j].y, acc[i][j]);
                            acc[i][j] = fmaf(rv.z, ev[j].z, acc[i][j]);
                            acc[i][j] = fmaf(rv.w, ev[j].w, acc[i][j]);
                        }
                    }
                }
            }

            float e2v[8];
            #pragma unroll
            for (int j = 0; j < 8; ++j)
                e2v[j] = e2g[s * KCODES + code0 + j * 64 + l];

            // ---- per-row top-1, numpy-exact dist & first-occurrence ties ----
            #pragma unroll
            for (int i = 0; i < 8; ++i) {
                float z2i = z2s[w * 8 + i];
                float m1 = 3.4e38f; int i1 = 0x7fffffff;
                #pragma unroll
                for (int j = 0; j < 8; ++j) {
                    float S = __fadd_rn(z2i, e2v[j]);      // fl(z2 + e2)
                    float v = fmaf(-2.f, acc[i][j], S);    // fl(S - 2*ze)
                    int cc = code0 + j * 64 + l;
                    if (v < m1) { m1 = v; i1 = cc; }       // ascending cc keeps first
                }
                #pragma unroll
                for (int d2 = 1; d2 < 64; d2 <<= 1) {
                    float ov = __shfl_xor(m1, d2); int oi = __shfl_xor(i1, d2);
                    if (ov < m1 || (ov == m1 && oi < i1)) { m1 = ov; i1 = oi; }
                }
                if (l == i) { top1v[p][w * 8 + i] = m1; top1i[p][w * 8 + i] = i1; }
            }
            __syncthreads();
        }

        // ---- merge passes (tie -> lower index = pass 0), emit code ----
        if (t < TM) {
            float av = top1v[0][t]; int ai = top1i[0][t];
            float bv = top1v[1][t]; int bi = top1i[1][t];
            int code = (bv < av) ? bi : ai;
            codes_s[t] = code;
            out[(size_t)BN * DDIM + (rowbase + t) * NQ + s] = (float)code;
        }
        __syncthreads();

        // ---- straight-through update, op-for-op numpy emulation ----
        {
            int c = codes_s[row_u];
            const float4* crow = (const float4*)(cbs + (size_t)c * DDIM + oct * 32);
            float4* rrow = (float4*)(&Rs[row_u][oct * 32]);
            float z2n = 0.f;
            #pragma unroll
            for (int n = 0; n < 8; ++n) {
                int i = (n + t) & 7;              // rotate -> spread LDS banks
                float4 rv = rrow[i];
                float4 cv = crow[i];
                float t1x = __fsub_rn(cv.x, rv.x), t1y = __fsub_rn(cv.y, rv.y);
                float t1z = __fsub_rn(cv.z, rv.z), t1w = __fsub_rn(cv.w, rv.w);
                lacc += (double)t1x * t1x + (double)t1y * t1y
                      + (double)t1z * t1z + (double)t1w * t1w;
                float qx = __fadd_rn(rv.x, t1x), qy = __fadd_rn(rv.y, t1y);
                float qz = __fadd_rn(rv.z, t1z), qw = __fadd_rn(rv.w, t1w);
                float nx = __fsub_rn(rv.x, qx), ny = __fsub_rn(rv.y, qy);
                float nz = __fsub_rn(rv.z, qz), nw = __fsub_rn(rv.w, qw);
                z2n = fmaf(nx, nx, z2n); z2n = fmaf(ny, ny, z2n);
                z2n = fmaf(nz, nz, z2n); z2n = fmaf(nw, nw, z2n);
                rrow[i] = make_float4(nx, ny, nz, nw);
            }
            z2n += __shfl_xor(z2n, 1);
            z2n += __shfl_xor(z2n, 2);
            z2n += __shfl_xor(z2n, 4);
            if (oct == 0) z2s[row_u] = z2n;
        }
        __syncthreads();
    }

    // ---- z_q_sum = z_e - residual_final (telescoped; tolerance-validated) ----
    {
        const float4* zsrc = (const float4*)(zin + rowbase * DDIM);
        const float4* rsrc = (const float4*)(&Rs[0][0]);
        float4* dst = (float4*)(out + rowbase * DDIM);
        #pragma unroll
        for (int n = 0; n < (TM * DDIM / 4) / THREADS; ++n) {
            int idx = t + n * THREADS;
            float4 a = zsrc[idx], r = rsrc[idx];
            a.x -= r.x; a.y -= r.y; a.z -= r.z; a.w -= r.w;
            dst[idx] = a;
        }
    }

    // ---- deterministic loss partial: wave shfl-reduce, then 4-way sum ----
    #pragma unroll
    for (int d2 = 1; d2 < 64; d2 <<= 1)
        lacc += __shfl_xor(lacc, d2);
    if (l == 0) lredw[w] = lacc;
    __syncthreads();
    if (t == 0)
        lossp[blockIdx.x] = (lredw[0] + lredw[1]) + (lredw[2] + lredw[3]);
}

__global__ void loss_final(const double* __restrict__ lossp, float* __restrict__ out) {
    double s = 0.0;
    for (int i = 0; i < BN / TM; ++i) s += lossp[i];
    out[(size_t)BN * DDIM + (size_t)BN * NQ] = (float)(1.25 * s / ((double)BN * (double)DDIM));
}

extern "C" void kernel_launch(void* const* d_in, const int* in_sizes, int n_in,
                              void* d_out, int out_size, void* d_ws, size_t ws_size,
                              hipStream_t stream) {
    const float* z_e = (const float*)d_in[0];
    const float* cb  = (const float*)d_in[1];
    float* out = (float*)d_out;
    float*  e2    = (float*)((char*)d_ws + WS_E2);
    double* lossp = (double*)((char*)d_ws + WS_LOSSP);
    float4* pk    = (float4*)((char*)d_ws + WS_PK);

    e2_kernel<<<dim3((NQ * KCODES) / 16), THREADS, 0, stream>>>(cb, e2);
    if (ws_size >= WS_NEED) {
        pack_kernel<<<dim3(NQ * NPASS * 64), THREADS, 0, stream>>>(cb, pk);
        rq_kernel<true><<<dim3(BN / TM), THREADS, 0, stream>>>(z_e, cb, e2, pk, out, lossp);
    } else {
        rq_kernel<false><<<dim3(BN / TM), THREADS, 0, stream>>>(z_e, cb, e2, pk, out, lossp);
    }
    loss_final<<<1, 1, 0, stream>>>(lossp, out);
}

// Round 8
// 2416.313 us; speedup vs baseline: 1.6434x; 1.6434x over previous
//
#include <hip/hip_runtime.h>
#include <math.h>

// ResidualQuantizer: 8 stages of VQ over B=32768 rows, D=256, K=1024.
// Outputs (flat f32): z_q_sum[32768*256], codes[32768*8] (as float), loss[1].
// Numerics: bit-exact numpy fp32 emulation for the argmin (proven r2..r7):
//   dist = fl(fl(z2 + e2_k) - 2*ze_k), ze_k = ascending-d fp32 FMA chain,
//   e2_k = numpy pairwise sum, argmin = first occurrence of min.
// Round 8: NO LDS staging, NO k-loop barriers. E is read directly from the
// packed (k-major) codebook in global memory — perfectly coalesced, L2/L3
// resident — into registers. LDS holds only the 32KB residual tile
// (broadcast reads). 4 blocks/CU. Waves fully decoupled in the k-loop.

#define NQ 8
#define KCODES 1024
#define DDIM 256
#define BN 32768
#define TM 32            // rows per block
#define THREADS 256
#define NKQ 64           // k-quads per row (DDIM/4)
#define CPP 512          // codes per pass
#define NPASS 2

#define WS_E2    0
#define WS_LOSSP 32768
#define WS_PK    40960
#define WS_NEED  (40960 + (size_t)NQ * KCODES * DDIM * 4)

// ---- e2[s*K+k] = np.sum(cb[s][k]**2), exact numpy pairwise emulation ----
__global__ void e2_kernel(const float* __restrict__ cb, float* __restrict__ e2) {
    __shared__ float X[16][DDIM];
    const int t = threadIdx.x;
    const int cbase = blockIdx.x * 16;
    {
        const float4* src = (const float4*)(cb + (size_t)cbase * DDIM);
        float4* dst = (float4*)(&X[0][0]);
        #pragma unroll
        for (int n = 0; n < 4; ++n) dst[t + n * THREADS] = src[t + n * THREADS];
    }
    __syncthreads();
    const int lane = t & 63;
    const int code = (t >> 6) * 4 + (lane >> 4);
    const int u = lane & 15, j = u & 7, h = u >> 3;
    const float* x = &X[code][h * 128];
    float r = __fmul_rn(x[j], x[j]);
    for (int i = 1; i < 16; ++i) {
        float v = x[8 * i + j];
        r = __fadd_rn(r, __fmul_rn(v, v));
    }
    float o;
    o = __shfl_xor(r, 1); r = __fadd_rn(r, o);
    o = __shfl_xor(r, 2); r = __fadd_rn(r, o);
    o = __shfl_xor(r, 4); r = __fadd_rn(r, o);
    o = __shfl_xor(r, 8); r = __fadd_rn(r, o);
    if (u == 0) e2[cbase + code] = r;
}

// ---- pack cb: pk[(sp*64+q)*512 + u] = cb[sp*512+u][q*4 .. q*4+4) ----
__global__ void pack_kernel(const float* __restrict__ cb, float4* __restrict__ pk) {
    const int t = threadIdx.x;
    const int bid = blockIdx.x;          // (s*2+p)*64 + q  (q = k-quad index)
    const int q = bid & 63, sp = bid >> 6;
    const float* src = cb + (size_t)sp * 512 * DDIM + q * 4;
    float4* dst = pk + (size_t)bid * 512;
    #pragma unroll
    for (int n = 0; n < 2; ++n) {
        int u = n * 256 + t;
        dst[u] = *(const float4*)(src + (size_t)u * DDIM);
    }
}

template <bool PACKED>
__global__ __launch_bounds__(THREADS, 4) void rq_kernel(
    const float* __restrict__ zin, const float* __restrict__ cb,
    const float* __restrict__ e2g, const float4* __restrict__ pk,
    float* __restrict__ out, double* __restrict__ lossp)
{
    __shared__ float  Rs[TM][DDIM];        // 32 KB residual tile (persistent)
    __shared__ float  top1v[NPASS][TM];
    __shared__ int    top1i[NPASS][TM];
    __shared__ float  z2s[TM];
    __shared__ int    codes_s[TM];
    __shared__ double lredw[4];

    const int t    = threadIdx.x;
    const int l    = t & 63;
    const int w    = t >> 6;               // wave id; wave w owns rows w*8..w*8+7
    const size_t rowbase = (size_t)blockIdx.x * TM;
    const int row_u = t >> 3, oct = t & 7;

    // ---- load residual tile = z_e rows (coalesced) ----
    {
        const float4* src = (const float4*)(zin + rowbase * DDIM);
        float4* dst = (float4*)(&Rs[0][0]);
        #pragma unroll
        for (int n = 0; n < (TM * DDIM / 4) / THREADS; ++n)
            dst[t + n * THREADS] = src[t + n * THREADS];
    }
    __syncthreads();

    // ---- initial z2 per row (uniform shift: any fp32 order OK — proven) ----
    {
        const float4* rrow = (const float4*)(&Rs[row_u][oct * 32]);
        float z2n = 0.f;
        #pragma unroll
        for (int i = 0; i < 8; ++i) {
            float4 rv = rrow[i];
            z2n = fmaf(rv.x, rv.x, z2n); z2n = fmaf(rv.y, rv.y, z2n);
            z2n = fmaf(rv.z, rv.z, z2n); z2n = fmaf(rv.w, rv.w, z2n);
        }
        z2n += __shfl_xor(z2n, 1);
        z2n += __shfl_xor(z2n, 2);
        z2n += __shfl_xor(z2n, 4);
        if (oct == 0) z2s[row_u] = z2n;
    }
    double lacc = 0.0;

    for (int s = 0; s < NQ; ++s) {
        const float* cbs = cb + (size_t)s * KCODES * DDIM;

        for (int p = 0; p < NPASS; ++p) {
            const int code0 = p * CPP;
            // direct-from-global E sources (lane-resolved bases)
            const float4* ep = pk + ((size_t)(s * 2 + p) * 64) * 512 + l;
            const float*  cp = cbs + (size_t)(code0 + l) * DDIM;

            float acc[8][8];
            #pragma unroll
            for (int i = 0; i < 8; ++i)
                #pragma unroll
                for (int j = 0; j < 8; ++j) acc[i][j] = 0.f;

            // ---- barrier-free k-loop: 8 coalesced global loads + 256 fmaf ----
            #pragma unroll 2
            for (int c = 0; c < NKQ; ++c) {
                float4 ev[8];
                #pragma unroll
                for (int j = 0; j < 8; ++j)
                    ev[j] = PACKED ? ep[(size_t)c * 512 + j * 64]
                                   : *(const float4*)(cp + (size_t)j * 64 * DDIM + c * 4);
                // ascending-d fp32 FMA chain (identical arithmetic to r2..r7)
                #pragma unroll
                for (int i = 0; i < 8; ++i) {
                    float4 rv = *(const float4*)(&Rs[w * 8 + i][c * 4]);   // broadcast
                    #pragma unroll
                    for (int j = 0; j < 8; ++j) {
                        acc[i][j] = fmaf(rv.x, ev[j].x, acc[i][j]);
                        acc[i][j] = fmaf(rv.y, ev[j].y, acc[i][j]);
                        acc[i][j] = fmaf(rv.z, ev[j].z, acc[i][j]);
                        acc[i][j] = fmaf(rv.w, ev[j].w, acc[i][j]);
                    }
                }
            }

            float e2v[8];
            #pragma unroll
            for (int j = 0; j < 8; ++j)
                e2v[j] = e2g[s * KCODES + code0 + j * 64 + l];

            // ---- per-row top-1, numpy-exact dist & first-occurrence ties ----
            #pragma unroll
            for (int i = 0; i < 8; ++i) {
                float z2i = z2s[w * 8 + i];
                float m1 = 3.4e38f; int i1 = 0x7fffffff;
                #pragma unroll
                for (int j = 0; j < 8; ++j) {
                    float S = __fadd_rn(z2i, e2v[j]);      // fl(z2 + e2)
                    float v = fmaf(-2.f, acc[i][j], S);    // fl(S - 2*ze)
                    int cc = code0 + j * 64 + l;
                    if (v < m1) { m1 = v; i1 = cc; }       // ascending cc keeps first
                }
                #pragma unroll
                for (int d2 = 1; d2 < 64; d2 <<= 1) {
                    float ov = __shfl_xor(m1, d2); int oi = __shfl_xor(i1, d2);
                    if (ov < m1 || (ov == m1 && oi < i1)) { m1 = ov; i1 = oi; }
                }
                if (l == i) { top1v[p][w * 8 + i] = m1; top1i[p][w * 8 + i] = i1; }
            }
            __syncthreads();
        }

        // ---- merge passes (tie -> lower index = pass 0), emit code ----
        if (t < TM) {
            float av = top1v[0][t]; int ai = top1i[0][t];
            float bv = top1v[1][t]; int bi = top1i[1][t];
            int code = (bv < av) ? bi : ai;
            codes_s[t] = code;
            out[(size_t)BN * DDIM + (rowbase + t) * NQ + s] = (float)code;
        }
        __syncthreads();

        // ---- straight-through update, op-for-op numpy emulation ----
        {
            int c = codes_s[row_u];
            const float4* crow = (const float4*)(cbs + (size_t)c * DDIM + oct * 32);
            float4* rrow = (float4*)(&Rs[row_u][oct * 32]);
            float z2n = 0.f;
            #pragma unroll
            for (int n = 0; n < 8; ++n) {
                int i = (n + t) & 7;              // rotate -> spread LDS banks
                float4 rv = rrow[i];
                float4 cv = crow[i];
                float t1x = __fsub_rn(cv.x, rv.x), t1y = __fsub_rn(cv.y, rv.y);
                float t1z = __fsub_rn(cv.z, rv.z), t1w = __fsub_rn(cv.w, rv.w);
                lacc += (double)t1x * t1x + (double)t1y * t1y
                      + (double)t1z * t1z + (double)t1w * t1w;
                float qx = __fadd_rn(rv.x, t1x), qy = __fadd_rn(rv.y, t1y);
                float qz = __fadd_rn(rv.z, t1z), qw = __fadd_rn(rv.w, t1w);
                float nx = __fsub_rn(rv.x, qx), ny = __fsub_rn(rv.y, qy);
                float nz = __fsub_rn(rv.z, qz), nw = __fsub_rn(rv.w, qw);
                z2n = fmaf(nx, nx, z2n); z2n = fmaf(ny, ny, z2n);
                z2n = fmaf(nz, nz, z2n); z2n = fmaf(nw, nw, z2n);
                rrow[i] = make_float4(nx, ny, nz, nw);
            }
            z2n += __shfl_xor(z2n, 1);
            z2n += __shfl_xor(z2n, 2);
            z2n += __shfl_xor(z2n, 4);
            if (oct == 0) z2s[row_u] = z2n;
        }
        __syncthreads();
    }

    // ---- z_q_sum = z_e - residual_final (telescoped; tolerance-validated) ----
    {
        const float4* zsrc = (const float4*)(zin + rowbase * DDIM);
        const float4* rsrc = (const float4*)(&Rs[0][0]);
        float4* dst = (float4*)(out + rowbase * DDIM);
        #pragma unroll
        for (int n = 0; n < (TM * DDIM / 4) / THREADS; ++n) {
            int idx = t + n * THREADS;
            float4 a = zsrc[idx], r = rsrc[idx];
            a.x -= r.x; a.y -= r.y; a.z -= r.z; a.w -= r.w;
            dst[idx] = a;
        }
    }

    // ---- deterministic loss partial: wave shfl-reduce, then 4-way sum ----
    #pragma unroll
    for (int d2 = 1; d2 < 64; d2 <<= 1)
        lacc += __shfl_xor(lacc, d2);
    if (l == 0) lredw[w] = lacc;
    __syncthreads();
    if (t == 0)
        lossp[blockIdx.x] = (lredw[0] + lredw[1]) + (lredw[2] + lredw[3]);
}

__global__ void loss_final(const double* __restrict__ lossp, float* __restrict__ out) {
    double s = 0.0;
    for (int i = 0; i < BN / TM; ++i) s += lossp[i];
    out[(size_t)BN * DDIM + (size_t)BN * NQ] = (float)(1.25 * s / ((double)BN * (double)DDIM));
}

extern "C" void kernel_launch(void* const* d_in, const int* in_sizes, int n_in,
                              void* d_out, int out_size, void* d_ws, size_t ws_size,
                              hipStream_t stream) {
    const float* z_e = (const float*)d_in[0];
    const float* cb  = (const float*)d_in[1];
    float* out = (float*)d_out;
    float*  e2    = (float*)((char*)d_ws + WS_E2);
    double* lossp = (double*)((char*)d_ws + WS_LOSSP);
    float4* pk    = (float4*)((char*)d_ws + WS_PK);

    e2_kernel<<<dim3((NQ * KCODES) / 16), THREADS, 0, stream>>>(cb, e2);
    if (ws_size >= WS_NEED) {
        pack_kernel<<<dim3(NQ * NPASS * 64), THREADS, 0, stream>>>(cb, pk);
        rq_kernel<true><<<dim3(BN / TM), THREADS, 0, stream>>>(z_e, cb, e2, pk, out, lossp);
    } else {
        rq_kernel<false><<<dim3(BN / TM), THREADS, 0, stream>>>(z_e, cb, e2, pk, out, lossp);
    }
    loss_final<<<1, 1, 0, stream>>>(lossp, out);
}

// Round 10
// 1158.711 us; speedup vs baseline: 3.4270x; 2.0853x over previous
//
#include <hip/hip_runtime.h>
#include <math.h>

// ResidualQuantizer: 8 stages of VQ over B=32768 rows, D=256, K=1024.
// Outputs (flat f32): z_q_sum[32768*256], codes[32768*8] (as float), loss[1].
// Round 10: MFMA filter + exact re-eval (r9 structure; overflow fixed).
//   - dist~ = e2 - 2*(Rh·Eh + Rl·Eh + Rh·El) via mfma_f32_16x16x32_bf16
//   - candidates { d~ <= subsetmin + W }, W=5e-4 >> 2*eps(~1.9e-4 worst)
//   - CAP=32; if a row's list overflows -> deterministic full 1024-code
//     exact re-scan (correctness unconditional; ~never taken)
//   - exact re-eval: proven numpy fp32 chain (r2..r8):
//       dist = fl(fl(z2+e2) - 2*ze), ze = ascending-d fmaf chain, lowest-index ties.

#define NQ 8
#define KCODES 1024
#define DDIM 256
#define BN 32768
#define TM 32
#define THREADS 256
#define NPASS 2
#define CPP 512
#define CAP 32
#define WFILT 5.0e-4f

#define WS_E2    0
#define WS_LOSSP 32768
#define WS_PKH   40960
#define WS_PKL   (40960 + 4194304)
#define WS_NEED  (40960 + 8388608)

typedef __attribute__((ext_vector_type(4))) float f32x4;
typedef __attribute__((ext_vector_type(8))) short s16x8;
union U4S8 { uint4 u; s16x8 s; };

__device__ __forceinline__ ushort f2bf(float x) {
    unsigned u = __float_as_uint(x);
    return (ushort)((u + 0x7fffu + ((u >> 16) & 1u)) >> 16);
}
__device__ __forceinline__ float bf2f(ushort h) {
    return __uint_as_float(((unsigned)h) << 16);
}

// exact numpy fp32 chain distance (minus z2 handled by caller adding S)
__device__ __forceinline__ float exact_dist(const float* __restrict__ rrow,
                                            const float* __restrict__ e,
                                            float z2, float e2v) {
    const float4* r4 = (const float4*)rrow;
    float a = 0.f;
    #pragma unroll 4
    for (int dq = 0; dq < 64; ++dq) {          // ascending-d fmaf chain
        float4 rv = r4[dq];
        float4 ev = *(const float4*)(e + dq * 4);
        a = fmaf(rv.x, ev.x, a);
        a = fmaf(rv.y, ev.y, a);
        a = fmaf(rv.z, ev.z, a);
        a = fmaf(rv.w, ev.w, a);
    }
    float S = __fadd_rn(z2, e2v);              // fl(z2 + e2)
    return fmaf(-2.f, a, S);                   // fl(S - 2*ze)
}

// ---- e2[s*K+k] = np.sum(cb[s][k]**2), exact numpy pairwise emulation ----
__global__ void e2_kernel(const float* __restrict__ cb, float* __restrict__ e2) {
    __shared__ float X[16][DDIM];
    const int t = threadIdx.x;
    const int cbase = blockIdx.x * 16;
    {
        const float4* src = (const float4*)(cb + (size_t)cbase * DDIM);
        float4* dst = (float4*)(&X[0][0]);
        #pragma unroll
        for (int n = 0; n < 4; ++n) dst[t + n * THREADS] = src[t + n * THREADS];
    }
    __syncthreads();
    const int lane = t & 63;
    const int code = (t >> 6) * 4 + (lane >> 4);
    const int u = lane & 15, j = u & 7, h = u >> 3;
    const float* x = &X[code][h * 128];
    float r = __fmul_rn(x[j], x[j]);
    for (int i = 1; i < 16; ++i) {
        float v = x[8 * i + j];
        r = __fadd_rn(r, __fmul_rn(v, v));
    }
    float o;
    o = __shfl_xor(r, 1); r = __fadd_rn(r, o);
    o = __shfl_xor(r, 2); r = __fadd_rn(r, o);
    o = __shfl_xor(r, 4); r = __fadd_rn(r, o);
    o = __shfl_xor(r, 8); r = __fadd_rn(r, o);
    if (u == 0) e2[cbase + code] = r;
}

// ---- pack codebook into MFMA B-fragment order, bf16 hi/lo split ----
// fragment (s, ks, gnt): lane l holds code gnt*16+(l&15), k = ks*32+(l>>4)*8 .. +8
__global__ void pack_kernel(const float* __restrict__ cb,
                            uint4* __restrict__ pkh, uint4* __restrict__ pkl) {
    const int bid = blockIdx.x;            // s*8 + ks
    const int s = bid >> 3, ks = bid & 7;
    const int t = threadIdx.x, sub = t >> 6, l = t & 63;
    const int k0 = ks * 32 + (l >> 4) * 8;
    const float* cbs = cb + (size_t)s * KCODES * DDIM;
    for (int it = 0; it < 16; ++it) {
        int gnt = it * 4 + sub;
        int code = gnt * 16 + (l & 15);
        const float* src = cbs + (size_t)code * DDIM + k0;
        float4 a = *(const float4*)(src);
        float4 b = *(const float4*)(src + 4);
        float xs[8] = {a.x, a.y, a.z, a.w, b.x, b.y, b.z, b.w};
        unsigned hh[4], ll[4];
        #pragma unroll
        for (int e = 0; e < 4; ++e) {
            ushort h0 = f2bf(xs[2*e]),   h1 = f2bf(xs[2*e+1]);
            ushort q0 = f2bf(xs[2*e] - bf2f(h0)), q1 = f2bf(xs[2*e+1] - bf2f(h1));
            hh[e] = (unsigned)h0 | ((unsigned)h1 << 16);
            ll[e] = (unsigned)q0 | ((unsigned)q1 << 16);
        }
        size_t idx = (((size_t)bid * 64 + gnt) << 6) + l;
        pkh[idx] = make_uint4(hh[0], hh[1], hh[2], hh[3]);
        pkl[idx] = make_uint4(ll[0], ll[1], ll[2], ll[3]);
    }
}

template <bool PACKED>
__global__ __launch_bounds__(THREADS, 2) void rq_kernel(
    const float* __restrict__ zin, const float* __restrict__ cb,
    const float* __restrict__ e2g,
    const uint4* __restrict__ pkh, const uint4* __restrict__ pkl,
    float* __restrict__ out, double* __restrict__ lossp)
{
    __shared__ float  Rs[TM][DDIM];        // 32 KB exact f32 residual
    __shared__ uint4  Rh4[TM * 32];        // 16 KB bf16-hi mirror, XOR-swizzled
    __shared__ uint4  Rl4[TM * 32];        // 16 KB bf16-lo mirror
    __shared__ int    list_s[TM][CAP];
    __shared__ int    cnt_s[TM];
    __shared__ float  z2s[TM];
    __shared__ int    codes_s[TM];
    __shared__ double lredw[4];

    const int t = threadIdx.x;
    const int l = t & 63;
    const int w = t >> 6;
    const int g = l >> 4;
    const size_t rowbase = (size_t)blockIdx.x * TM;
    const int row_u = t >> 3, oct = t & 7;
    char* RhB = (char*)Rh4;
    char* RlB = (char*)Rl4;

    // ---- load residual tile = z_e rows (coalesced) ----
    {
        const float4* src = (const float4*)(zin + rowbase * DDIM);
        float4* dst = (float4*)(&Rs[0][0]);
        #pragma unroll
        for (int n = 0; n < (TM * DDIM / 4) / THREADS; ++n)
            dst[t + n * THREADS] = src[t + n * THREADS];
    }
    if (t < TM) cnt_s[t] = 0;
    __syncthreads();

    // ---- initial z2 + bf16 hi/lo mirrors ----
    {
        const float4* rrow = (const float4*)(&Rs[row_u][oct * 32]);
        const int sw = (row_u & 7) << 4;
        const int byte0 = row_u * 512 + oct * 64;
        float z2n = 0.f;
        #pragma unroll
        for (int i = 0; i < 8; ++i) {
            float4 rv = rrow[i];
            z2n = fmaf(rv.x, rv.x, z2n); z2n = fmaf(rv.y, rv.y, z2n);
            z2n = fmaf(rv.z, rv.z, z2n); z2n = fmaf(rv.w, rv.w, z2n);
            ushort hx = f2bf(rv.x), hy = f2bf(rv.y), hz = f2bf(rv.z), hw = f2bf(rv.w);
            int ad = (byte0 + i * 8) ^ sw;
            *(uint2*)(RhB + ad) = make_uint2((unsigned)hx | ((unsigned)hy << 16),
                                             (unsigned)hz | ((unsigned)hw << 16));
            ushort lx = f2bf(rv.x - bf2f(hx)), ly = f2bf(rv.y - bf2f(hy));
            ushort lz = f2bf(rv.z - bf2f(hz)), lw = f2bf(rv.w - bf2f(hw));
            *(uint2*)(RlB + ad) = make_uint2((unsigned)lx | ((unsigned)ly << 16),
                                             (unsigned)lz | ((unsigned)lw << 16));
        }
        z2n += __shfl_xor(z2n, 1);
        z2n += __shfl_xor(z2n, 2);
        z2n += __shfl_xor(z2n, 4);
        if (oct == 0) z2s[row_u] = z2n;
    }
    double lacc = 0.0;
    __syncthreads();

    for (int s = 0; s < NQ; ++s) {
        const float* cbs = cb + (size_t)s * KCODES * DDIM;

        for (int p = 0; p < NPASS; ++p) {
            const int gnt0 = p * 32 + w * 8;   // wave's first global 16-code tile

            f32x4 acc[2][8];
            #pragma unroll
            for (int m = 0; m < 2; ++m)
                #pragma unroll
                for (int nt = 0; nt < 8; ++nt)
                    acc[m][nt] = (f32x4){0.f, 0.f, 0.f, 0.f};

            // ---- MFMA over K=256 (8 k-steps of 32) ----
            #pragma unroll 1
            for (int ks = 0; ks < 8; ++ks) {
                const int abyte = ((l & 15) << 9) + ((ks * 32 + g * 8) << 1);
                const int a0 = abyte ^ ((l & 7) << 4);
                U4S8 ah0, al0, ah1, al1;
                ah0.u = *(const uint4*)(RhB + a0);
                al0.u = *(const uint4*)(RlB + a0);
                ah1.u = *(const uint4*)(RhB + (a0 + 8192));
                al1.u = *(const uint4*)(RlB + (a0 + 8192));
                #pragma unroll
                for (int nt = 0; nt < 8; ++nt) {
                    U4S8 bh, bl;
                    if (PACKED) {
                        size_t fidx = (((size_t)((s * 8 + ks) * 64 + gnt0 + nt)) << 6) + l;
                        bh.u = pkh[fidx];
                        bl.u = pkl[fidx];
                    } else {
                        int code = (gnt0 + nt) * 16 + (l & 15);
                        const float* src = cbs + (size_t)code * DDIM + ks * 32 + g * 8;
                        float4 aa = *(const float4*)src;
                        float4 bb = *(const float4*)(src + 4);
                        float xs[8] = {aa.x, aa.y, aa.z, aa.w, bb.x, bb.y, bb.z, bb.w};
                        unsigned hh[4], ll2[4];
                        #pragma unroll
                        for (int e = 0; e < 4; ++e) {
                            ushort h0 = f2bf(xs[2*e]),   h1 = f2bf(xs[2*e+1]);
                            ushort q0 = f2bf(xs[2*e] - bf2f(h0)), q1 = f2bf(xs[2*e+1] - bf2f(h1));
                            hh[e]  = (unsigned)h0 | ((unsigned)h1 << 16);
                            ll2[e] = (unsigned)q0 | ((unsigned)q1 << 16);
                        }
                        bh.u = make_uint4(hh[0], hh[1], hh[2], hh[3]);
                        bl.u = make_uint4(ll2[0], ll2[1], ll2[2], ll2[3]);
                    }
                    acc[0][nt] = __builtin_amdgcn_mfma_f32_16x16x32_bf16(ah0.s, bh.s, acc[0][nt], 0, 0, 0);
                    acc[0][nt] = __builtin_amdgcn_mfma_f32_16x16x32_bf16(al0.s, bh.s, acc[0][nt], 0, 0, 0);
                    acc[0][nt] = __builtin_amdgcn_mfma_f32_16x16x32_bf16(ah0.s, bl.s, acc[0][nt], 0, 0, 0);
                    acc[1][nt] = __builtin_amdgcn_mfma_f32_16x16x32_bf16(ah1.s, bh.s, acc[1][nt], 0, 0, 0);
                    acc[1][nt] = __builtin_amdgcn_mfma_f32_16x16x32_bf16(al1.s, bh.s, acc[1][nt], 0, 0, 0);
                    acc[1][nt] = __builtin_amdgcn_mfma_f32_16x16x32_bf16(ah1.s, bl.s, acc[1][nt], 0, 0, 0);
                }
            }

            // ---- filter: subset min + candidate collection ----
            float e2f[8];
            #pragma unroll
            for (int nt = 0; nt < 8; ++nt)
                e2f[nt] = e2g[s * KCODES + (gnt0 + nt) * 16 + (l & 15)];

            #pragma unroll
            for (int m = 0; m < 2; ++m)
            #pragma unroll
            for (int r = 0; r < 4; ++r) {
                float mn = 3.4e38f;
                #pragma unroll
                for (int nt = 0; nt < 8; ++nt)
                    mn = fminf(mn, fmaf(-2.f, acc[m][nt][r], e2f[nt]));
                #pragma unroll
                for (int d2 = 1; d2 < 16; d2 <<= 1)
                    mn = fminf(mn, __shfl_xor(mn, d2));
                const float thr = mn + WFILT;
                const int row = m * 16 + g * 4 + r;
                #pragma unroll
                for (int nt = 0; nt < 8; ++nt) {
                    float v = fmaf(-2.f, acc[m][nt][r], e2f[nt]);
                    unsigned long long mask = __ballot(v <= thr);
                    if ((l & 15) == 0) {
                        unsigned msk = (unsigned)((mask >> (g * 16)) & 0xffffu);
                        if (msk) {
                            int n = __builtin_popcount(msk);
                            int base = atomicAdd(&cnt_s[row], n);
                            int cb16 = (gnt0 + nt) * 16;
                            int i = 0;
                            while (msk) {
                                int b = __builtin_ctz(msk); msk &= msk - 1;
                                if (base + i < CAP) list_s[row][base + i] = cb16 + b;
                                ++i;
                            }
                        }
                    }
                }
            }
        }
        __syncthreads();   // candidate lists complete

        // ---- exact re-eval (proven chain); overflow -> full 1024 re-scan ----
        {
            const int row = row_u, sl = oct;
            const int nc = cnt_s[row];
            const float z2i = z2s[row];
            float bv = 3.4e38f; int bi = 0x7fffffff;
            if (nc > CAP) {
                // deterministic fallback: scan every code (~never taken)
                for (int c = sl; c < KCODES; c += 8) {
                    float v = exact_dist(&Rs[row][0], cbs + (size_t)c * DDIM,
                                         z2i, e2g[s * KCODES + c]);
                    if (v < bv || (v == bv && c < bi)) { bv = v; bi = c; }
                }
            } else {
                for (int ci = sl; ci < nc; ci += 8) {
                    int c = list_s[row][ci];
                    float v = exact_dist(&Rs[row][0], cbs + (size_t)c * DDIM,
                                         z2i, e2g[s * KCODES + c]);
                    if (v < bv || (v == bv && c < bi)) { bv = v; bi = c; }
                }
            }
            #pragma unroll
            for (int d2 = 1; d2 < 8; d2 <<= 1) {
                float ov = __shfl_xor(bv, d2);
                int   oi = __shfl_xor(bi, d2);
                if (ov < bv || (ov == bv && oi < bi)) { bv = ov; bi = oi; }
            }
            if (sl == 0) {
                codes_s[row] = bi;
                cnt_s[row] = 0;                 // reset for next stage
                out[(size_t)BN * DDIM + (rowbase + row) * NQ + s] = (float)bi;
            }
        }
        __syncthreads();

        // ---- straight-through update (verbatim) + refresh bf16 mirrors ----
        {
            int c = codes_s[row_u];
            const float4* crow = (const float4*)(cbs + (size_t)c * DDIM + oct * 32);
            float4* rrow = (float4*)(&Rs[row_u][oct * 32]);
            const int sw = (row_u & 7) << 4;
            const int byte0 = row_u * 512 + oct * 64;
            float z2n = 0.f;
            #pragma unroll
            for (int n = 0; n < 8; ++n) {
                int i = (n + t) & 7;
                float4 rv = rrow[i];
                float4 cv = crow[i];
                float t1x = __fsub_rn(cv.x, rv.x), t1y = __fsub_rn(cv.y, rv.y);
                float t1z = __fsub_rn(cv.z, rv.z), t1w = __fsub_rn(cv.w, rv.w);
                lacc += (double)t1x * t1x + (double)t1y * t1y
                      + (double)t1z * t1z + (double)t1w * t1w;
                float qx = __fadd_rn(rv.x, t1x), qy = __fadd_rn(rv.y, t1y);
                float qz = __fadd_rn(rv.z, t1z), qw = __fadd_rn(rv.w, t1w);
                float nx = __fsub_rn(rv.x, qx), ny = __fsub_rn(rv.y, qy);
                float nz = __fsub_rn(rv.z, qz), nw = __fsub_rn(rv.w, qw);
                z2n = fmaf(nx, nx, z2n); z2n = fmaf(ny, ny, z2n);
                z2n = fmaf(nz, nz, z2n); z2n = fmaf(nw, nw, z2n);
                rrow[i] = make_float4(nx, ny, nz, nw);
                ushort hx = f2bf(nx), hy = f2bf(ny), hz = f2bf(nz), hw = f2bf(nw);
                int ad = (byte0 + i * 8) ^ sw;
                *(uint2*)(RhB + ad) = make_uint2((unsigned)hx | ((unsigned)hy << 16),
                                                 (unsigned)hz | ((unsigned)hw << 16));
                ushort lx = f2bf(nx - bf2f(hx)), ly = f2bf(ny - bf2f(hy));
                ushort lz = f2bf(nz - bf2f(hz)), lw = f2bf(nw - bf2f(hw));
                *(uint2*)(RlB + ad) = make_uint2((unsigned)lx | ((unsigned)ly << 16),
                                                 (unsigned)lz | ((unsigned)lw << 16));
            }
            z2n += __shfl_xor(z2n, 1);
            z2n += __shfl_xor(z2n, 2);
            z2n += __shfl_xor(z2n, 4);
            if (oct == 0) z2s[row_u] = z2n;
        }
        __syncthreads();
    }

    // ---- z_q_sum = z_e - residual_final (telescoped; tolerance-validated) ----
    {
        const float4* zsrc = (const float4*)(zin + rowbase * DDIM);
        const float4* rsrc = (const float4*)(&Rs[0][0]);
        float4* dst = (float4*)(out + rowbase * DDIM);
        #pragma unroll
        for (int n = 0; n < (TM * DDIM / 4) / THREADS; ++n) {
            int idx = t + n * THREADS;
            float4 a = zsrc[idx], r = rsrc[idx];
            a.x -= r.x; a.y -= r.y; a.z -= r.z; a.w -= r.w;
            dst[idx] = a;
        }
    }

    // ---- deterministic loss partial ----
    #pragma unroll
    for (int d2 = 1; d2 < 64; d2 <<= 1)
        lacc += __shfl_xor(lacc, d2);
    if (l == 0) lredw[w] = lacc;
    __syncthreads();
    if (t == 0)
        lossp[blockIdx.x] = (lredw[0] + lredw[1]) + (lredw[2] + lredw[3]);
}

__global__ void loss_final(const double* __restrict__ lossp, float* __restrict__ out) {
    double s = 0.0;
    for (int i = 0; i < BN / TM; ++i) s += lossp[i];
    out[(size_t)BN * DDIM + (size_t)BN * NQ] = (float)(1.25 * s / ((double)BN * (double)DDIM));
}

extern "C" void kernel_launch(void* const* d_in, const int* in_sizes, int n_in,
                              void* d_out, int out_size, void* d_ws, size_t ws_size,
                              hipStream_t stream) {
    const float* z_e = (const float*)d_in[0];
    const float* cb  = (const float*)d_in[1];
    float* out = (float*)d_out;
    float*  e2    = (float*)((char*)d_ws + WS_E2);
    double* lossp = (double*)((char*)d_ws + WS_LOSSP);
    uint4*  pkh   = (uint4*)((char*)d_ws + WS_PKH);
    uint4*  pkl   = (uint4*)((char*)d_ws + WS_PKL);

    e2_kernel<<<dim3((NQ * KCODES) / 16), THREADS, 0, stream>>>(cb, e2);
    if (ws_size >= WS_NEED) {
        pack_kernel<<<dim3(NQ * 8), THREADS, 0, stream>>>(cb, pkh, pkl);
        rq_kernel<true><<<dim3(BN / TM), THREADS, 0, stream>>>(z_e, cb, e2, pkh, pkl, out, lossp);
    } else {
        rq_kernel<false><<<dim3(BN / TM), THREADS, 0, stream>>>(z_e, cb, e2, pkh, pkl, out, lossp);
    }
    loss_final<<<1, 1, 0, stream>>>(lossp, out);
}

// Round 11
// 854.852 us; speedup vs baseline: 4.6452x; 1.3555x over previous
//
#include <hip/hip_runtime.h>
#include <math.h>

// ResidualQuantizer: 8 stages of VQ over B=32768 rows, D=256, K=1024.
// Outputs (flat f32): z_q_sum[32768*256], codes[32768*8] (as float), loss[1].
// Round 11: r10 MFMA-filter structure, restructured for TLP:
//   - 512 threads/block, 8 wave-subsets, single filter pass (4 waves/SIMD)
//   - A-mirrors stored in MFMA fragment order [half][ks][lane] -> conflict-free
//   - numerics identical to r10: dist~ via 3x mfma_f32_16x16x32_bf16 hi/lo,
//     candidates { d~ <= subsetmin + W }, exact numpy fp32 chain re-eval,
//     overflow -> full exact scan. z2-order invariance proven (ulp-shift arg).

#define NQ 8
#define KCODES 1024
#define DDIM 256
#define BN 32768
#define TM 32
#define THREADS 512
#define CAP 32
#define WFILT 5.0e-4f

#define WS_E2    0
#define WS_LOSSP 32768
#define WS_PKH   40960
#define WS_PKL   (40960 + 4194304)
#define WS_NEED  (40960 + 8388608)

typedef __attribute__((ext_vector_type(4))) float f32x4;
typedef __attribute__((ext_vector_type(8))) short s16x8;
union U4S8 { uint4 u; s16x8 s; };

__device__ __forceinline__ ushort f2bf(float x) {
    unsigned u = __float_as_uint(x);
    return (ushort)((u + 0x7fffu + ((u >> 16) & 1u)) >> 16);
}
__device__ __forceinline__ float bf2f(ushort h) {
    return __uint_as_float(((unsigned)h) << 16);
}

// exact numpy fp32 chain distance (proven bit-exact r2..r10)
__device__ __forceinline__ float exact_dist(const float* __restrict__ rrow,
                                            const float* __restrict__ e,
                                            float z2, float e2v) {
    const float4* r4 = (const float4*)rrow;
    float a = 0.f;
    #pragma unroll 4
    for (int dq = 0; dq < 64; ++dq) {          // ascending-d fmaf chain
        float4 rv = r4[dq];
        float4 ev = *(const float4*)(e + dq * 4);
        a = fmaf(rv.x, ev.x, a);
        a = fmaf(rv.y, ev.y, a);
        a = fmaf(rv.z, ev.z, a);
        a = fmaf(rv.w, ev.w, a);
    }
    float S = __fadd_rn(z2, e2v);              // fl(z2 + e2)
    return fmaf(-2.f, a, S);                   // fl(S - 2*ze)
}

// ---- e2[s*K+k] = np.sum(cb[s][k]**2), exact numpy pairwise emulation ----
__global__ void e2_kernel(const float* __restrict__ cb, float* __restrict__ e2) {
    __shared__ float X[16][DDIM];
    const int t = threadIdx.x;
    const int cbase = blockIdx.x * 16;
    {
        const float4* src = (const float4*)(cb + (size_t)cbase * DDIM);
        float4* dst = (float4*)(&X[0][0]);
        #pragma unroll
        for (int n = 0; n < 4; ++n) dst[t + n * 256] = src[t + n * 256];
    }
    __syncthreads();
    const int lane = t & 63;
    const int code = (t >> 6) * 4 + (lane >> 4);
    const int u = lane & 15, j = u & 7, h = u >> 3;
    const float* x = &X[code][h * 128];
    float r = __fmul_rn(x[j], x[j]);
    for (int i = 1; i < 16; ++i) {
        float v = x[8 * i + j];
        r = __fadd_rn(r, __fmul_rn(v, v));
    }
    float o;
    o = __shfl_xor(r, 1); r = __fadd_rn(r, o);
    o = __shfl_xor(r, 2); r = __fadd_rn(r, o);
    o = __shfl_xor(r, 4); r = __fadd_rn(r, o);
    o = __shfl_xor(r, 8); r = __fadd_rn(r, o);
    if (u == 0) e2[cbase + code] = r;
}

// ---- pack codebook into MFMA B-fragment order, bf16 hi/lo split ----
// fragment (s, ks, gnt): lane l holds code gnt*16+(l&15), k = ks*32+(l>>4)*8 .. +8
__global__ void pack_kernel(const float* __restrict__ cb,
                            uint4* __restrict__ pkh, uint4* __restrict__ pkl) {
    const int bid = blockIdx.x;            // s*8 + ks
    const int s = bid >> 3, ks = bid & 7;
    const int t = threadIdx.x, sub = t >> 6, l = t & 63;
    const int k0 = ks * 32 + (l >> 4) * 8;
    const float* cbs = cb + (size_t)s * KCODES * DDIM;
    for (int it = 0; it < 16; ++it) {
        int gnt = it * 4 + sub;
        int code = gnt * 16 + (l & 15);
        const float* src = cbs + (size_t)code * DDIM + k0;
        float4 a = *(const float4*)(src);
        float4 b = *(const float4*)(src + 4);
        float xs[8] = {a.x, a.y, a.z, a.w, b.x, b.y, b.z, b.w};
        unsigned hh[4], ll[4];
        #pragma unroll
        for (int e = 0; e < 4; ++e) {
            ushort h0 = f2bf(xs[2*e]),   h1 = f2bf(xs[2*e+1]);
            ushort q0 = f2bf(xs[2*e] - bf2f(h0)), q1 = f2bf(xs[2*e+1] - bf2f(h1));
            hh[e] = (unsigned)h0 | ((unsigned)h1 << 16);
            ll[e] = (unsigned)q0 | ((unsigned)q1 << 16);
        }
        size_t idx = (((size_t)bid * 64 + gnt) << 6) + l;
        pkh[idx] = make_uint4(hh[0], hh[1], hh[2], hh[3]);
        pkl[idx] = make_uint4(ll[0], ll[1], ll[2], ll[3]);
    }
}

template <bool PACKED>
__global__ __launch_bounds__(THREADS, 4) void rq_kernel(
    const float* __restrict__ zin, const float* __restrict__ cb,
    const float* __restrict__ e2g,
    const uint4* __restrict__ pkh, const uint4* __restrict__ pkl,
    float* __restrict__ out, double* __restrict__ lossp)
{
    __shared__ float  Rs[TM][DDIM];        // 32 KB exact f32 residual
    __shared__ uint4  RhF[16 * 64];        // 16 KB bf16-hi mirror, fragment order
    __shared__ uint4  RlF[16 * 64];        // 16 KB bf16-lo mirror, fragment order
    __shared__ int    list_s[TM][CAP];
    __shared__ int    cnt_s[TM];
    __shared__ float  z2s[TM];
    __shared__ int    codes_s[TM];
    __shared__ double lredw[8];

    const int t = threadIdx.x;
    const int l = t & 63;
    const int w = t >> 6;                   // 8 waves
    const int g = l >> 4;
    const size_t rowbase = (size_t)blockIdx.x * TM;

    // ---- load residual tile = z_e rows (coalesced) ----
    {
        const float4* src = (const float4*)(zin + rowbase * DDIM);
        float4* dst = (float4*)(&Rs[0][0]);
        #pragma unroll
        for (int n = 0; n < (TM * DDIM / 4) / THREADS; ++n)   // 4
            dst[t + n * THREADS] = src[t + n * THREADS];
    }
    if (t < TM) cnt_s[t] = 0;
    __syncthreads();

    // ---- initial z2 + fragment-order bf16 mirrors (threads 0-255) ----
    if (t < 256) {
        const int row = t >> 3, oct = t & 7;
        const float4* rrow = (const float4*)(&Rs[row][oct * 32]);
        float z2n = 0.f;
        uint2 hi2[8], lo2[8];
        #pragma unroll
        for (int n = 0; n < 8; ++n) {
            float4 rv = rrow[n];
            z2n = fmaf(rv.x, rv.x, z2n); z2n = fmaf(rv.y, rv.y, z2n);
            z2n = fmaf(rv.z, rv.z, z2n); z2n = fmaf(rv.w, rv.w, z2n);
            ushort hx = f2bf(rv.x), hy = f2bf(rv.y), hz = f2bf(rv.z), hw = f2bf(rv.w);
            hi2[n] = make_uint2((unsigned)hx | ((unsigned)hy << 16),
                                (unsigned)hz | ((unsigned)hw << 16));
            ushort lx = f2bf(rv.x - bf2f(hx)), ly = f2bf(rv.y - bf2f(hy));
            ushort lz = f2bf(rv.z - bf2f(hz)), lw = f2bf(rv.w - bf2f(hw));
            lo2[n] = make_uint2((unsigned)lx | ((unsigned)ly << 16),
                                (unsigned)lz | ((unsigned)lw << 16));
        }
        const int fbase = ((row >> 4) * 8 + oct) * 64 + (row & 15);
        #pragma unroll
        for (int q = 0; q < 4; ++q) {
            RhF[fbase + 16 * q] = make_uint4(hi2[2*q].x, hi2[2*q].y,
                                             hi2[2*q+1].x, hi2[2*q+1].y);
            RlF[fbase + 16 * q] = make_uint4(lo2[2*q].x, lo2[2*q].y,
                                             lo2[2*q+1].x, lo2[2*q+1].y);
        }
        z2n += __shfl_xor(z2n, 1);
        z2n += __shfl_xor(z2n, 2);
        z2n += __shfl_xor(z2n, 4);
        if (oct == 0) z2s[row] = z2n;
    }
    double lacc = 0.0;
    __syncthreads();

    for (int s = 0; s < NQ; ++s) {
        const float* cbs = cb + (size_t)s * KCODES * DDIM;
        const int gnt0 = w * 8;             // wave's 8 global 16-code tiles

        f32x4 acc[2][8];
        #pragma unroll
        for (int m = 0; m < 2; ++m)
            #pragma unroll
            for (int nt = 0; nt < 8; ++nt)
                acc[m][nt] = (f32x4){0.f, 0.f, 0.f, 0.f};

        // ---- MFMA over K=256 (8 k-steps of 32); A reads conflict-free ----
        #pragma unroll 1
        for (int ks = 0; ks < 8; ++ks) {
            U4S8 ah0, al0, ah1, al1;
            ah0.u = RhF[ks * 64 + l];
            al0.u = RlF[ks * 64 + l];
            ah1.u = RhF[(8 + ks) * 64 + l];
            al1.u = RlF[(8 + ks) * 64 + l];
            #pragma unroll
            for (int nt = 0; nt < 8; ++nt) {
                U4S8 bh, bl;
                if (PACKED) {
                    size_t fidx = (((size_t)((s * 8 + ks) * 64 + gnt0 + nt)) << 6) + l;
                    bh.u = pkh[fidx];
                    bl.u = pkl[fidx];
                } else {
                    int code = (gnt0 + nt) * 16 + (l & 15);
                    const float* src = cbs + (size_t)code * DDIM + ks * 32 + g * 8;
                    float4 aa = *(const float4*)src;
                    float4 bb = *(const float4*)(src + 4);
                    float xs[8] = {aa.x, aa.y, aa.z, aa.w, bb.x, bb.y, bb.z, bb.w};
                    unsigned hh[4], ll2[4];
                    #pragma unroll
                    for (int e = 0; e < 4; ++e) {
                        ushort h0 = f2bf(xs[2*e]),   h1 = f2bf(xs[2*e+1]);
                        ushort q0 = f2bf(xs[2*e] - bf2f(h0)), q1 = f2bf(xs[2*e+1] - bf2f(h1));
                        hh[e]  = (unsigned)h0 | ((unsigned)h1 << 16);
                        ll2[e] = (unsigned)q0 | ((unsigned)q1 << 16);
                    }
                    bh.u = make_uint4(hh[0], hh[1], hh[2], hh[3]);
                    bl.u = make_uint4(ll2[0], ll2[1], ll2[2], ll2[3]);
                }
                acc[0][nt] = __builtin_amdgcn_mfma_f32_16x16x32_bf16(ah0.s, bh.s, acc[0][nt], 0, 0, 0);
                acc[0][nt] = __builtin_amdgcn_mfma_f32_16x16x32_bf16(al0.s, bh.s, acc[0][nt], 0, 0, 0);
                acc[0][nt] = __builtin_amdgcn_mfma_f32_16x16x32_bf16(ah0.s, bl.s, acc[0][nt], 0, 0, 0);
                acc[1][nt] = __builtin_amdgcn_mfma_f32_16x16x32_bf16(ah1.s, bh.s, acc[1][nt], 0, 0, 0);
                acc[1][nt] = __builtin_amdgcn_mfma_f32_16x16x32_bf16(al1.s, bh.s, acc[1][nt], 0, 0, 0);
                acc[1][nt] = __builtin_amdgcn_mfma_f32_16x16x32_bf16(ah1.s, bl.s, acc[1][nt], 0, 0, 0);
            }
        }

        // ---- filter: subset min + candidate collection (identical to r10) ----
        {
            float e2f[8];
            #pragma unroll
            for (int nt = 0; nt < 8; ++nt)
                e2f[nt] = e2g[s * KCODES + (gnt0 + nt) * 16 + (l & 15)];

            #pragma unroll
            for (int m = 0; m < 2; ++m)
            #pragma unroll
            for (int r = 0; r < 4; ++r) {
                float mn = 3.4e38f;
                #pragma unroll
                for (int nt = 0; nt < 8; ++nt)
                    mn = fminf(mn, fmaf(-2.f, acc[m][nt][r], e2f[nt]));
                #pragma unroll
                for (int d2 = 1; d2 < 16; d2 <<= 1)
                    mn = fminf(mn, __shfl_xor(mn, d2));
                const float thr = mn + WFILT;
                const int row = m * 16 + g * 4 + r;
                #pragma unroll
                for (int nt = 0; nt < 8; ++nt) {
                    float v = fmaf(-2.f, acc[m][nt][r], e2f[nt]);
                    unsigned long long mask = __ballot(v <= thr);
                    if ((l & 15) == 0) {
                        unsigned msk = (unsigned)((mask >> (g * 16)) & 0xffffu);
                        if (msk) {
                            int n = __builtin_popcount(msk);
                            int base = atomicAdd(&cnt_s[row], n);
                            int cb16 = (gnt0 + nt) * 16;
                            int i = 0;
                            while (msk) {
                                int b = __builtin_ctz(msk); msk &= msk - 1;
                                if (base + i < CAP) list_s[row][base + i] = cb16 + b;
                                ++i;
                            }
                        }
                    }
                }
            }
        }
        __syncthreads();   // candidate lists complete

        // ---- exact re-eval, 16 lanes/row (min-lattice: order-independent) ----
        {
            const int row = t >> 4, sl = t & 15;
            const int nc = cnt_s[row];
            const float z2i = z2s[row];
            float bv = 3.4e38f; int bi = 0x7fffffff;
            if (nc > CAP) {
                for (int c = sl; c < KCODES; c += 16) {
                    float v = exact_dist(&Rs[row][0], cbs + (size_t)c * DDIM,
                                         z2i, e2g[s * KCODES + c]);
                    if (v < bv || (v == bv && c < bi)) { bv = v; bi = c; }
                }
            } else {
                for (int ci = sl; ci < nc; ci += 16) {
                    int c = list_s[row][ci];
                    float v = exact_dist(&Rs[row][0], cbs + (size_t)c * DDIM,
                                         z2i, e2g[s * KCODES + c]);
                    if (v < bv || (v == bv && c < bi)) { bv = v; bi = c; }
                }
            }
            #pragma unroll
            for (int d2 = 1; d2 < 16; d2 <<= 1) {
                float ov = __shfl_xor(bv, d2);
                int   oi = __shfl_xor(bi, d2);
                if (ov < bv || (ov == bv && oi < bi)) { bv = ov; bi = oi; }
            }
            if (sl == 0) {
                codes_s[row] = bi;
                cnt_s[row] = 0;                 // reset for next stage
                out[(size_t)BN * DDIM + (rowbase + row) * NQ + s] = (float)bi;
            }
        }
        __syncthreads();

        // ---- straight-through update (threads 0-255; r10 arithmetic) ----
        if (t < 256) {
            const int row = t >> 3, oct = t & 7;
            int c = codes_s[row];
            const float4* crow = (const float4*)(cbs + (size_t)c * DDIM + oct * 32);
            float4* rrow = (float4*)(&Rs[row][oct * 32]);
            float z2n = 0.f;
            uint2 hi2[8], lo2[8];
            #pragma unroll
            for (int n = 0; n < 8; ++n) {
                float4 rv = rrow[n];
                float4 cv = crow[n];
                float t1x = __fsub_rn(cv.x, rv.x), t1y = __fsub_rn(cv.y, rv.y);
                float t1z = __fsub_rn(cv.z, rv.z), t1w = __fsub_rn(cv.w, rv.w);
                lacc += (double)t1x * t1x + (double)t1y * t1y
                      + (double)t1z * t1z + (double)t1w * t1w;
                float qx = __fadd_rn(rv.x, t1x), qy = __fadd_rn(rv.y, t1y);
                float qz = __fadd_rn(rv.z, t1z), qw = __fadd_rn(rv.w, t1w);
                float nx = __fsub_rn(rv.x, qx), ny = __fsub_rn(rv.y, qy);
                float nz = __fsub_rn(rv.z, qz), nw = __fsub_rn(rv.w, qw);
                z2n = fmaf(nx, nx, z2n); z2n = fmaf(ny, ny, z2n);
                z2n = fmaf(nz, nz, z2n); z2n = fmaf(nw, nw, z2n);
                rrow[n] = make_float4(nx, ny, nz, nw);
                ushort hx = f2bf(nx), hy = f2bf(ny), hz = f2bf(nz), hw = f2bf(nw);
                hi2[n] = make_uint2((unsigned)hx | ((unsigned)hy << 16),
                                    (unsigned)hz | ((unsigned)hw << 16));
                ushort lx = f2bf(nx - bf2f(hx)), ly = f2bf(ny - bf2f(hy));
                ushort lz = f2bf(nz - bf2f(hz)), lw = f2bf(nw - bf2f(hw));
                lo2[n] = make_uint2((unsigned)lx | ((unsigned)ly << 16),
                                    (unsigned)lz | ((unsigned)lw << 16));
            }
            const int fbase = ((row >> 4) * 8 + oct) * 64 + (row & 15);
            #pragma unroll
            for (int q = 0; q < 4; ++q) {
                RhF[fbase + 16 * q] = make_uint4(hi2[2*q].x, hi2[2*q].y,
                                                 hi2[2*q+1].x, hi2[2*q+1].y);
                RlF[fbase + 16 * q] = make_uint4(lo2[2*q].x, lo2[2*q].y,
                                                 lo2[2*q+1].x, lo2[2*q+1].y);
            }
            z2n += __shfl_xor(z2n, 1);
            z2n += __shfl_xor(z2n, 2);
            z2n += __shfl_xor(z2n, 4);
            if (oct == 0) z2s[row] = z2n;
        }
        __syncthreads();
    }

    // ---- z_q_sum = z_e - residual_final (telescoped; tolerance-validated) ----
    {
        const float4* zsrc = (const float4*)(zin + rowbase * DDIM);
        const float4* rsrc = (const float4*)(&Rs[0][0]);
        float4* dst = (float4*)(out + rowbase * DDIM);
        #pragma unroll
        for (int n = 0; n < (TM * DDIM / 4) / THREADS; ++n) {
            int idx = t + n * THREADS;
            float4 a = zsrc[idx], r = rsrc[idx];
            a.x -= r.x; a.y -= r.y; a.z -= r.z; a.w -= r.w;
            dst[idx] = a;
        }
    }

    // ---- deterministic loss partial ----
    #pragma unroll
    for (int d2 = 1; d2 < 64; d2 <<= 1)
        lacc += __shfl_xor(lacc, d2);
    if (l == 0) lredw[w] = lacc;
    __syncthreads();
    if (t == 0) {
        double s2 = 0.0;
        #pragma unroll
        for (int i = 0; i < 8; ++i) s2 += lredw[i];
        lossp[blockIdx.x] = s2;
    }
}

__global__ void loss_final(const double* __restrict__ lossp, float* __restrict__ out) {
    double s = 0.0;
    for (int i = 0; i < BN / TM; ++i) s += lossp[i];
    out[(size_t)BN * DDIM + (size_t)BN * NQ] = (float)(1.25 * s / ((double)BN * (double)DDIM));
}

extern "C" void kernel_launch(void* const* d_in, const int* in_sizes, int n_in,
                              void* d_out, int out_size, void* d_ws, size_t ws_size,
                              hipStream_t stream) {
    const float* z_e = (const float*)d_in[0];
    const float* cb  = (const float*)d_in[1];
    float* out = (float*)d_out;
    float*  e2    = (float*)((char*)d_ws + WS_E2);
    double* lossp = (double*)((char*)d_ws + WS_LOSSP);
    uint4*  pkh   = (uint4*)((char*)d_ws + WS_PKH);
    uint4*  pkl   = (uint4*)((char*)d_ws + WS_PKL);

    e2_kernel<<<dim3((NQ * KCODES) / 16), 256, 0, stream>>>(cb, e2);
    if (ws_size >= WS_NEED) {
        pack_kernel<<<dim3(NQ * 8), 256, 0, stream>>>(cb, pkh, pkl);
        rq_kernel<true><<<dim3(BN / TM), THREADS, 0, stream>>>(z_e, cb, e2, pkh, pkl, out, lossp);
    } else {
        rq_kernel<false><<<dim3(BN / TM), THREADS, 0, stream>>>(z_e, cb, e2, pkh, pkl, out, lossp);
    }
    loss_final<<<1, 1, 0, stream>>>(lossp, out);
}